// Round 7
// baseline (194.558 us; speedup 1.0000x reference)
//
#include <hip/hip_runtime.h>
#include <math.h>

#define B_ 4
#define T_ 4096
#define C_ 1024
#define H_ 64
#define NROW (B_ * T_)  // 16384

typedef unsigned short u16;
typedef __attribute__((ext_vector_type(8))) short short8;
typedef __attribute__((ext_vector_type(4))) float floatx4;
typedef __attribute__((ext_vector_type(8))) unsigned short ushortx8;
typedef __attribute__((ext_vector_type(4))) unsigned short ushortx4;

__device__ __forceinline__ u16 f2bf(float f) {  // RNE
  unsigned int u = __builtin_bit_cast(unsigned int, f);
  unsigned int r = (u + 0x7FFFu + ((u >> 16) & 1u)) >> 16;
  return (u16)r;
}

// ---------------------------------------------------------------------------
// Cast Wq|Wk|Wv fp32 -> Wb bf16 [192][1024]. grid 192 x 256.
// ---------------------------------------------------------------------------
__global__ __launch_bounds__(256) void cast_w_kernel(
    const float* __restrict__ Wq, const float* __restrict__ Wk,
    const float* __restrict__ Wv, u16* __restrict__ Wb) {
  int i = blockIdx.x * 256 + threadIdx.x;  // float4 index, 49152 total
  const float* src = (i < 16384) ? Wq : ((i < 32768) ? Wk : Wv);
  int j = i & 16383;
  float4 v = ((const float4*)src)[j];
  ushortx4 o = {f2bf(v.x), f2bf(v.y), f2bf(v.z), f2bf(v.w)};
  *(ushortx4*)(Wb + (size_t)i * 4) = o;
}

// ---------------------------------------------------------------------------
// Projection partials, split-k=2. One wave = 16 rows x 192 cols, k-half.
// grid (1024, 2) x 64 thr = 2048 waves = 8 waves/CU.
// Phase 1 stages x (fp32->bf16) into LDS -> the k-loop's ONLY vmem is W
// (L2-resident): a single pure in-order vmcnt stream (R5/R6 lesson: mixing
// HBM-x and L2-W on one counter serializes every step at HBM latency).
// Writes fp32 partial acc; projcomb sums the two halves.
// ---------------------------------------------------------------------------
__global__ __launch_bounds__(64) void projpart_kernel(
    const float* __restrict__ x, const u16* __restrict__ Wb,
    float* __restrict__ Ppart) {
  const int m0 = (int)blockIdx.x * 16;
  const int kh = (int)blockIdx.y;  // k in [kh*512, kh*512+512)
  const int lane = threadIdx.x;
  const int lq = lane & 15, quad = lane >> 4;

  __shared__ __align__(16) u16 xs[16][528];  // bf16 x tile, padded rows

  const float* xg = x + (size_t)m0 * C_ + kh * 512;
#pragma unroll
  for (int i = 0; i < 16; ++i) {
    float4 a = *(const float4*)(xg + (size_t)i * C_ + lane * 8);
    float4 b = *(const float4*)(xg + (size_t)i * C_ + lane * 8 + 4);
    ushortx8 v = {f2bf(a.x), f2bf(a.y), f2bf(a.z), f2bf(a.w),
                  f2bf(b.x), f2bf(b.y), f2bf(b.z), f2bf(b.w)};
    *(ushortx8*)&xs[i][lane * 8] = v;
  }
  __builtin_amdgcn_s_waitcnt(0);  // single wave: drain before LDS reads

  floatx4 acc[12];
#pragma unroll
  for (int i = 0; i < 12; ++i) acc[i] = (floatx4){0.f, 0.f, 0.f, 0.f};

  const u16* wrow = Wb + (size_t)lq * C_ + kh * 512 + quad * 8;
#pragma unroll
  for (int ks = 0; ks < 512; ks += 32) {
    short8 af = *(const short8*)&xs[lq][ks + quad * 8];
#pragma unroll
    for (int nt = 0; nt < 12; ++nt) {
      short8 bf = *(const short8*)(wrow + (size_t)nt * 16 * C_ + ks);
      acc[nt] = __builtin_amdgcn_mfma_f32_16x16x32_bf16(af, bf, acc[nt], 0, 0, 0);
    }
  }

  float* P = Ppart + (size_t)kh * NROW * 192;
#pragma unroll
  for (int nt = 0; nt < 12; ++nt)
#pragma unroll
    for (int r = 0; r < 4; ++r)
      P[(size_t)(m0 + quad * 4 + r) * 192 + nt * 16 + lq] = acc[nt][r];
}

// ---------------------------------------------------------------------------
// Sum the two k-half partials, cast bf16, write Qb (x0.125), Kb, Vt
// (transposed [b][h][t]). Block 256 = 64 rows; grid 256.
// ---------------------------------------------------------------------------
__global__ __launch_bounds__(256) void projcomb_kernel(
    const float* __restrict__ Ppart, u16* __restrict__ Qb,
    u16* __restrict__ Kb, u16* __restrict__ Vt) {
  const int m0 = (int)blockIdx.x * 64;
  const int tid = threadIdx.x;
  __shared__ __align__(16) u16 sm[64][208];  // summed bf16, cols 0..191

  const float* P0 = Ppart;
  const float* P1 = Ppart + (size_t)NROW * 192;
#pragma unroll
  for (int i = 0; i < 12; ++i) {
    int idx = tid + i * 256;  // 0..3071 float4s (64 rows x 48 f4)
    int row = idx / 48;
    int c4 = idx - row * 48;
    size_t off = (size_t)(m0 + row) * 192 + c4 * 4;
    float4 a = *(const float4*)(P0 + off);
    float4 b = *(const float4*)(P1 + off);
    float s0 = a.x + b.x, s1 = a.y + b.y, s2 = a.z + b.z, s3 = a.w + b.w;
    if (c4 < 16) { s0 *= 0.125f; s1 *= 0.125f; s2 *= 0.125f; s3 *= 0.125f; }
    ushortx4 v = {f2bf(s0), f2bf(s1), f2bf(s2), f2bf(s3)};
    *(ushortx4*)&sm[row][c4 * 4] = v;
  }
  __syncthreads();

  const int row = tid >> 2, hseg = (tid & 3) * 16;
  {
    ushortx8 w0 = *(const ushortx8*)&sm[row][hseg];
    ushortx8 w1 = *(const ushortx8*)&sm[row][hseg + 8];
    u16* dq = Qb + (size_t)(m0 + row) * H_ + hseg;
    *(ushortx8*)dq = w0;
    *(ushortx8*)(dq + 8) = w1;
  }
  {
    ushortx8 w0 = *(const ushortx8*)&sm[row][64 + hseg];
    ushortx8 w1 = *(const ushortx8*)&sm[row][64 + hseg + 8];
    u16* dk = Kb + (size_t)(m0 + row) * H_ + hseg;
    *(ushortx8*)dk = w0;
    *(ushortx8*)(dk + 8) = w1;
  }
  {
    const int h = tid >> 2, tseg = (tid & 3) * 16;
    u16 tmp[16];
#pragma unroll
    for (int tt = 0; tt < 16; ++tt) tmp[tt] = sm[tseg + tt][128 + h];
    ushortx8 w0, w1;
#pragma unroll
    for (int tt = 0; tt < 8; ++tt) { w0[tt] = tmp[tt]; w1[tt] = tmp[8 + tt]; }
    const int bb = m0 >> 12, t0 = m0 & 4095;
    u16* dv = Vt + ((size_t)bb * H_ + h) * T_ + t0 + tseg;
    *(ushortx8*)dv = w0;
    *(ushortx8*)(dv + 8) = w1;
  }
}

// ---------------------------------------------------------------------------
// Flash attention v3. Block = 256 thr (4 waves), Q-tile 128 (32 rows/wave).
// K/V 64-key chunks staged cooperatively into XOR-SWIZZLED unpadded LDS
// (16B chunk (row,c) at slot row*8 + (c^(row&7)): staging writes AND frag
// reads are uniform 8 lanes/bank-quad, all 16B-aligned). Double-buffered,
// ONE barrier/chunk; 3 blocks/CU (LDS 51.2 KB) hide each other's barrier
// drains (R6's 1-wave version de-pipelined under register pressure: 240
// VGPRs < demand -> prefetch descheduled -> 3000 cyc/chunk serial).
// Split-K (fixed-offset softmax p=exp(s-4): partials add). grid (32, B*KS).
// ---------------------------------------------------------------------------
__global__ __launch_bounds__(256) void attn_kernel(
    const u16* __restrict__ Qb, const u16* __restrict__ Kb,
    const u16* __restrict__ Vt, float* __restrict__ Opart,
    float* __restrict__ lpart, int KS, int kslog) {
  const int tau = (int)gridDim.x - 1 - (int)blockIdx.x;  // LPT: heavy first
  const int q0 = tau * 128;
  const int b = (int)blockIdx.y >> kslog;
  const int s = (int)blockIdx.y & (KS - 1);
  const int tid = threadIdx.x;
  const int wave = tid >> 6, lane = tid & 63;
  const int lq = lane & 15, quad = lane >> 4;
  const int sw = lq & 7;

  __shared__ __align__(16) u16 ksh[2][64 * 64];
  __shared__ __align__(16) u16 vsh[2][64 * 64];
  __shared__ __align__(16) u16 ps[4][32 * 72];

  const int nch = 2 * tau + 2;  // 64-key chunks incl. diagonal
  const u16* Kb_b = Kb + (size_t)b * T_ * H_;
  const u16* Vt_b = Vt + (size_t)b * H_ * T_;

  short8 qa[2][2];
#pragma unroll
  for (int rt = 0; rt < 2; ++rt) {
    const u16* qrow =
        Qb + ((size_t)b * T_ + q0 + wave * 32 + rt * 16 + lq) * H_;
    qa[rt][0] = *(const short8*)(qrow + quad * 8);
    qa[rt][1] = *(const short8*)(qrow + 32 + quad * 8);
  }

  floatx4 o[2][4];
  float lrow[2][4];
#pragma unroll
  for (int rt = 0; rt < 2; ++rt)
#pragma unroll
    for (int t = 0; t < 4; ++t) {
      o[rt][t] = (floatx4){0.f, 0.f, 0.f, 0.f};
      lrow[rt][t] = 0.f;
    }

  // staging map: thread covers 16B chunks c=tid and c=tid+256 of the 512
  const int srow = tid >> 3;  // 0..31
  const int sseg = tid & 7;
  const int spos0 = (srow * 8 + (sseg ^ (srow & 7))) * 8;  // u16 index
  const int spos1 = spos0 + 2048;                          // row+32, same xor

  int4 kst0, kst1, vst0, vst1;
#define STAGE_LOAD(S0)                                                        \
  {                                                                           \
    kst0 = *(const int4*)(Kb_b + (size_t)((S0) + srow) * H_ + sseg * 8);      \
    kst1 = *(const int4*)(Kb_b + (size_t)((S0) + srow + 32) * H_ + sseg * 8); \
    vst0 = *(const int4*)(Vt_b + (size_t)srow * T_ + (S0) + sseg * 8);        \
    vst1 = *(const int4*)(Vt_b + (size_t)(srow + 32) * T_ + (S0) + sseg * 8); \
  }
#define STAGE_WRITE(BUF)                                                      \
  {                                                                           \
    *(int4*)&ksh[BUF][spos0] = kst0;                                          \
    *(int4*)&ksh[BUF][spos1] = kst1;                                          \
    *(int4*)&vsh[BUF][spos0] = vst0;                                          \
    *(int4*)&vsh[BUF][spos1] = vst1;                                          \
  }

  int ch = s, buf = 0;
  if (ch < nch) {
    STAGE_LOAD(ch * 64)
    STAGE_WRITE(0)
  }
  __syncthreads();

  if (ch < nch) {
    for (;;) {
      const bool have_next = (ch + KS < nch);
      if (have_next) { STAGE_LOAD((ch + KS) * 64) }
      const int s0 = ch * 64;

      // ---- S = Q @ K^T ----
      floatx4 sf[2][4];
#pragma unroll
      for (int t = 0; t < 4; ++t) {
        const int row8 = (t * 16 + lq) * 8;
        short8 kb0 = *(const short8*)&ksh[buf][(row8 + (quad ^ sw)) * 8];
        short8 kb1 = *(const short8*)&ksh[buf][(row8 + ((quad + 4) ^ sw)) * 8];
#pragma unroll
        for (int rt = 0; rt < 2; ++rt) {
          floatx4 z = (floatx4){0.f, 0.f, 0.f, 0.f};
          z = __builtin_amdgcn_mfma_f32_16x16x32_bf16(qa[rt][0], kb0, z, 0, 0, 0);
          z = __builtin_amdgcn_mfma_f32_16x16x32_bf16(qa[rt][1], kb1, z, 0, 0, 0);
          sf[rt][t] = z;
        }
      }

      // ---- softmax with fixed offset; causal mask (interior chunks never
      // trigger the compare, so unconditional cndmask is correct) ----
#pragma unroll
      for (int rt = 0; rt < 2; ++rt)
#pragma unroll
        for (int t = 0; t < 4; ++t)
#pragma unroll
          for (int r = 0; r < 4; ++r) {
            float p = __expf(sf[rt][t][r] - 4.0f);
            if (s0 + t * 16 + lq > q0 + wave * 32 + rt * 16 + quad * 4 + r)
              p = 0.f;
            lrow[rt][r] += p;
            ps[wave][(rt * 16 + quad * 4 + r) * 72 + t * 16 + lq] = f2bf(p);
          }

      // ---- O += P @ V (P via per-wave LDS round-trip; same-wave DS order) --
      short8 pa[2][2];
#pragma unroll
      for (int rt = 0; rt < 2; ++rt) {
        pa[rt][0] = *(const short8*)&ps[wave][(rt * 16 + lq) * 72 + quad * 8];
        pa[rt][1] =
            *(const short8*)&ps[wave][(rt * 16 + lq) * 72 + 32 + quad * 8];
      }
#pragma unroll
      for (int t = 0; t < 4; ++t) {
        const int row8 = (t * 16 + lq) * 8;
        short8 vb0 = *(const short8*)&vsh[buf][(row8 + (quad ^ sw)) * 8];
        short8 vb1 = *(const short8*)&vsh[buf][(row8 + ((quad + 4) ^ sw)) * 8];
#pragma unroll
        for (int rt = 0; rt < 2; ++rt) {
          o[rt][t] = __builtin_amdgcn_mfma_f32_16x16x32_bf16(pa[rt][0], vb0,
                                                             o[rt][t], 0, 0, 0);
          o[rt][t] = __builtin_amdgcn_mfma_f32_16x16x32_bf16(pa[rt][1], vb1,
                                                             o[rt][t], 0, 0, 0);
        }
      }

      if (!have_next) break;
      STAGE_WRITE(buf ^ 1)
      __syncthreads();
      buf ^= 1;
      ch += KS;
    }
  }

#pragma unroll
  for (int rt = 0; rt < 2; ++rt)
#pragma unroll
    for (int r = 0; r < 4; ++r) {
#pragma unroll
      for (int off = 1; off < 16; off <<= 1)
        lrow[rt][r] += __shfl_xor(lrow[rt][r], off);
    }

  const size_t prow = (size_t)((b << kslog) + s) * T_ + q0 + wave * 32;
#pragma unroll
  for (int rt = 0; rt < 2; ++rt) {
#pragma unroll
    for (int t = 0; t < 4; ++t)
#pragma unroll
      for (int r = 0; r < 4; ++r)
        Opart[(prow + rt * 16 + quad * 4 + r) * H_ + t * 16 + lq] =
            o[rt][t][r];
    if (lq == 0) {
#pragma unroll
      for (int r = 0; r < 4; ++r)
        lpart[prow + rt * 16 + quad * 4 + r] = lrow[rt][r];
    }
  }
}

// ---------------------------------------------------------------------------
// Combine: out[b][t][h] = Sum_s Opart / Sum_s lpart. grid 1024 x 256.
// ---------------------------------------------------------------------------
__global__ __launch_bounds__(256) void combine_kernel(
    const float* __restrict__ Opart, const float* __restrict__ lpart,
    float* __restrict__ out, int KS, int kslog) {
  int gid = blockIdx.x * 256 + threadIdx.x;  // 262144 float4 groups
  int b = gid >> 16;
  int rem = gid & 65535;
  int t = rem >> 4;
  int hs = (rem & 15) * 4;
  float sx = 0.f, sy = 0.f, sz = 0.f, sw = 0.f, ls = 0.f;
  for (int s = 0; s < KS; ++s) {
    size_t row = (size_t)((b << kslog) + s) * T_ + t;
    float4 v = *(const float4*)(Opart + row * H_ + hs);
    sx += v.x; sy += v.y; sz += v.z; sw += v.w;
    ls += lpart[row];
  }
  float inv = 1.f / ls;
  float4 o = make_float4(sx * inv, sy * inv, sz * inv, sw * inv);
  *(float4*)(out + ((size_t)b * T_ + t) * H_ + hs) = o;
}

extern "C" void kernel_launch(void* const* d_in, const int* in_sizes, int n_in,
                              void* d_out, int out_size, void* d_ws, size_t ws_size,
                              hipStream_t stream) {
  const float* x = (const float*)d_in[0];
  const float* Wq = (const float*)d_in[1];
  const float* Wk = (const float*)d_in[2];
  const float* Wv = (const float*)d_in[3];
  u16* Qb = (u16*)d_ws;                    // [16384][64] bf16, pre-scaled 1/8
  u16* Kb = Qb + (size_t)NROW * H_;        // [16384][64] bf16
  u16* Vt = Kb + (size_t)NROW * H_;        // [4][64][4096] bf16 (transposed)
  u16* Wb = Vt + (size_t)NROW * H_;        // [192][1024] bf16
  const size_t base = (size_t)3 * NROW * H_ * 2 + 192 * 1024 * 2;  // 6.68 MB

  const size_t ppart_sz = (size_t)2 * NROW * 192 * 4;  // 25.2 MB fp32 partials
  int KS = 8;
  while (KS > 1) {
    size_t osz = (size_t)KS * ((size_t)B_ * T_ * H_ * 4 + (size_t)B_ * T_ * 4);
    size_t need = base + (osz > ppart_sz ? osz : ppart_sz);
    if (need <= ws_size) break;
    KS >>= 1;
  }
  int kslog = (KS == 8) ? 3 : (KS == 4) ? 2 : (KS == 2) ? 1 : 0;

  // Ppart and Opart alias the same region (sequential lifetimes).
  float* Ppart = (float*)((char*)d_ws + base);
  float* Opart = Ppart;
  float* lpart = Opart + (size_t)KS * B_ * T_ * H_;
  float* out = (float*)d_out;

  cast_w_kernel<<<dim3(192), 256, 0, stream>>>(Wq, Wk, Wv, Wb);
  projpart_kernel<<<dim3(1024, 2), 64, 0, stream>>>(x, Wb, Ppart);
  projcomb_kernel<<<dim3(256), 256, 0, stream>>>(Ppart, Qb, Kb, Vt);
  attn_kernel<<<dim3(32, B_ * KS), 256, 0, stream>>>(Qb, Kb, Vt, Opart, lpart,
                                                     KS, kslog);
  combine_kernel<<<dim3(1024), 256, 0, stream>>>(Opart, lpart, out, KS, kslog);
}

// Round 8
// 186.972 us; speedup vs baseline: 1.0406x; 1.0406x over previous
//
#include <hip/hip_runtime.h>
#include <math.h>

#define B_ 4
#define T_ 4096
#define C_ 1024
#define H_ 64
#define NROW (B_ * T_)  // 16384

typedef unsigned short u16;
typedef __attribute__((ext_vector_type(8))) short short8;
typedef __attribute__((ext_vector_type(4))) float floatx4;
typedef __attribute__((ext_vector_type(8))) unsigned short ushortx8;
typedef __attribute__((ext_vector_type(4))) unsigned short ushortx4;

__device__ __forceinline__ u16 f2bf(float f) {  // RNE
  unsigned int u = __builtin_bit_cast(unsigned int, f);
  unsigned int r = (u + 0x7FFFu + ((u >> 16) & 1u)) >> 16;
  return (u16)r;
}

// ---------------------------------------------------------------------------
// Cast Wq|Wk|Wv fp32 -> Wb bf16 [192][1024]. grid 192 x 256.
// ---------------------------------------------------------------------------
__global__ __launch_bounds__(256) void cast_w_kernel(
    const float* __restrict__ Wq, const float* __restrict__ Wk,
    const float* __restrict__ Wv, u16* __restrict__ Wb) {
  int i = blockIdx.x * 256 + threadIdx.x;  // float4 index, 49152 total
  const float* src = (i < 16384) ? Wq : ((i < 32768) ? Wk : Wv);
  int j = i & 16383;
  float4 v = ((const float4*)src)[j];
  ushortx4 o = {f2bf(v.x), f2bf(v.y), f2bf(v.z), f2bf(v.w)};
  *(ushortx4*)(Wb + (size_t)i * 4) = o;
}

// ---------------------------------------------------------------------------
// QKV projection v7 (single kernel). One wave = 16 rows x 192 cols, K=1024.
// grid 1024 x 64 thr (4 waves/CU).
//  - x tile staged ONCE to LDS as bf16 (coalesced; one-time drain) -> the
//    k-loop's only global traffic is W.
//  - W B-frags in an explicit depth-2 register ring wf[3][12] (~190 VGPRs,
//    plain __launch_bounds__(64) = demand-driven allocation). R7's projpart
//    failed because VGPR=72 left no room to prefetch -> every k-step ate L2
//    latency serially (MfmaUtil 3.3%). R3's attn proved this exact pattern.
//  - Epilogue: verified proj4/proj5 fragments write Qb(x0.125)/Kb/Vt
//    directly; the 50 MB Ppart round-trip + projcomb launch are deleted.
// ---------------------------------------------------------------------------
__global__ __launch_bounds__(64) void proj7_kernel(
    const float* __restrict__ x, const u16* __restrict__ Wb,
    u16* __restrict__ Qb, u16* __restrict__ Kb, u16* __restrict__ Vt) {
  const int m0 = (int)blockIdx.x * 16;
  const int lane = threadIdx.x;
  const int lq = lane & 15, quad = lane >> 4;

  __shared__ __align__(16) u16 xs[16][1032];  // bf16 x tile (pad 8 -> 2-way)
  __shared__ __align__(16) u16 stg[16][72];   // Q/K epilogue staging
  __shared__ __align__(16) u16 vstg[64 * 32]; // V transpose staging

  // ---- stage x row-tile fp32->bf16 into LDS (one-time, coalesced) ----
#pragma unroll 4
  for (int j = 0; j < 32; ++j) {
    int g = j * 64 + lane;
    int row = g >> 7, col = (g & 127) * 8;
    const float* src = x + (size_t)(m0 + row) * C_ + col;
    float4 a = *(const float4*)(src);
    float4 b = *(const float4*)(src + 4);
    ushortx8 v = {f2bf(a.x), f2bf(a.y), f2bf(a.z), f2bf(a.w),
                  f2bf(b.x), f2bf(b.y), f2bf(b.z), f2bf(b.w)};
    *(ushortx8*)&xs[row][col] = v;
  }
  __builtin_amdgcn_s_waitcnt(0);  // single wave: drain before ds_read

  floatx4 acc[12];
#pragma unroll
  for (int i = 0; i < 12; ++i) acc[i] = (floatx4){0.f, 0.f, 0.f, 0.f};

  const u16* wp = Wb + (size_t)lq * C_ + quad * 8;

  // ---- k-loop: 32 steps of k=32; W-frag ring depth 2 ----
  short8 wf[3][12];
#pragma unroll
  for (int nt = 0; nt < 12; ++nt)
    wf[0][nt] = *(const short8*)(wp + (size_t)nt * 16 * C_);
#pragma unroll
  for (int nt = 0; nt < 12; ++nt)
    wf[1][nt] = *(const short8*)(wp + (size_t)nt * 16 * C_ + 32);

#pragma unroll
  for (int s = 0; s < 32; ++s) {
    short8 af = *(const short8*)&xs[lq][s * 32 + quad * 8];
    if (s + 2 < 32) {
#pragma unroll
      for (int nt = 0; nt < 12; ++nt)
        wf[(s + 2) % 3][nt] =
            *(const short8*)(wp + (size_t)nt * 16 * C_ + (s + 2) * 32);
    }
#pragma unroll
    for (int nt = 0; nt < 12; ++nt)
      acc[nt] = __builtin_amdgcn_mfma_f32_16x16x32_bf16(af, wf[s % 3][nt],
                                                        acc[nt], 0, 0, 0);
  }

  // ---- epilogue: Q (x0.125) and K via stg (verified pattern) ----
#pragma unroll
  for (int mat = 0; mat < 2; ++mat) {
    const float sc = (mat == 0) ? 0.125f : 1.0f;  // fold 64^-0.5 into Q
#pragma unroll
    for (int nt = 0; nt < 4; ++nt)
#pragma unroll
      for (int r = 0; r < 4; ++r)
        stg[quad * 4 + r][nt * 16 + lq] = f2bf(acc[mat * 4 + nt][r] * sc);
    __builtin_amdgcn_s_waitcnt(0);
    const int mrow = lane >> 2, cs = (lane & 3) * 16;
    ushortx8 w0 = *(const ushortx8*)&stg[mrow][cs];
    ushortx8 w1 = *(const ushortx8*)&stg[mrow][cs + 8];
    u16* dst = ((mat == 0) ? Qb : Kb) + (size_t)(m0 + mrow) * H_ + cs;
    *(ushortx8*)(dst) = w0;
    *(ushortx8*)(dst + 8) = w1;
    __builtin_amdgcn_s_waitcnt(0);  // stg reused next mat (W-A-R)
  }

  // ---- V: transpose to Vt[b][h][t] ----
#pragma unroll
  for (int nt = 0; nt < 4; ++nt)
#pragma unroll
    for (int r = 0; r < 4; ++r)
      vstg[(nt * 16 + lq) * 32 + quad * 4 + r] = f2bf(acc[8 + nt][r]);
  __builtin_amdgcn_s_waitcnt(0);
  {
    const int bb = m0 >> 12, t0 = m0 & 4095;
    ushortx8 w0 = *(const ushortx8*)&vstg[lane * 32];
    ushortx8 w1 = *(const ushortx8*)&vstg[lane * 32 + 8];
    u16* dst = Vt + ((size_t)bb * H_ + lane) * T_ + t0;
    *(ushortx8*)(dst) = w0;
    *(ushortx8*)(dst + 8) = w1;
  }
}

// ---------------------------------------------------------------------------
// Flash attention v3 (unchanged from R7). Block = 256 thr (4 waves), Q-tile
// 128 (32 rows/wave). K/V 64-key chunks staged cooperatively into
// XOR-swizzled unpadded LDS, double-buffered, one barrier/chunk. Split-K
// (fixed-offset softmax p=exp(s-4): partials add). grid (32, B*KS).
// ---------------------------------------------------------------------------
__global__ __launch_bounds__(256) void attn_kernel(
    const u16* __restrict__ Qb, const u16* __restrict__ Kb,
    const u16* __restrict__ Vt, float* __restrict__ Opart,
    float* __restrict__ lpart, int KS, int kslog) {
  const int tau = (int)gridDim.x - 1 - (int)blockIdx.x;  // LPT: heavy first
  const int q0 = tau * 128;
  const int b = (int)blockIdx.y >> kslog;
  const int s = (int)blockIdx.y & (KS - 1);
  const int tid = threadIdx.x;
  const int wave = tid >> 6, lane = tid & 63;
  const int lq = lane & 15, quad = lane >> 4;
  const int sw = lq & 7;

  __shared__ __align__(16) u16 ksh[2][64 * 64];
  __shared__ __align__(16) u16 vsh[2][64 * 64];
  __shared__ __align__(16) u16 ps[4][32 * 72];

  const int nch = 2 * tau + 2;  // 64-key chunks incl. diagonal
  const u16* Kb_b = Kb + (size_t)b * T_ * H_;
  const u16* Vt_b = Vt + (size_t)b * H_ * T_;

  short8 qa[2][2];
#pragma unroll
  for (int rt = 0; rt < 2; ++rt) {
    const u16* qrow =
        Qb + ((size_t)b * T_ + q0 + wave * 32 + rt * 16 + lq) * H_;
    qa[rt][0] = *(const short8*)(qrow + quad * 8);
    qa[rt][1] = *(const short8*)(qrow + 32 + quad * 8);
  }

  floatx4 o[2][4];
  float lrow[2][4];
#pragma unroll
  for (int rt = 0; rt < 2; ++rt)
#pragma unroll
    for (int t = 0; t < 4; ++t) {
      o[rt][t] = (floatx4){0.f, 0.f, 0.f, 0.f};
      lrow[rt][t] = 0.f;
    }

  // staging map: thread covers 16B chunks c=tid and c=tid+256 of the 512
  const int srow = tid >> 3;  // 0..31
  const int sseg = tid & 7;
  const int spos0 = (srow * 8 + (sseg ^ (srow & 7))) * 8;  // u16 index
  const int spos1 = spos0 + 2048;                          // row+32, same xor

  int4 kst0, kst1, vst0, vst1;
#define STAGE_LOAD(S0)                                                        \
  {                                                                           \
    kst0 = *(const int4*)(Kb_b + (size_t)((S0) + srow) * H_ + sseg * 8);      \
    kst1 = *(const int4*)(Kb_b + (size_t)((S0) + srow + 32) * H_ + sseg * 8); \
    vst0 = *(const int4*)(Vt_b + (size_t)srow * T_ + (S0) + sseg * 8);        \
    vst1 = *(const int4*)(Vt_b + (size_t)(srow + 32) * T_ + (S0) + sseg * 8); \
  }
#define STAGE_WRITE(BUF)                                                      \
  {                                                                           \
    *(int4*)&ksh[BUF][spos0] = kst0;                                          \
    *(int4*)&ksh[BUF][spos1] = kst1;                                          \
    *(int4*)&vsh[BUF][spos0] = vst0;                                          \
    *(int4*)&vsh[BUF][spos1] = vst1;                                          \
  }

  int ch = s, buf = 0;
  if (ch < nch) {
    STAGE_LOAD(ch * 64)
    STAGE_WRITE(0)
  }
  __syncthreads();

  if (ch < nch) {
    for (;;) {
      const bool have_next = (ch + KS < nch);
      if (have_next) { STAGE_LOAD((ch + KS) * 64) }
      const int s0 = ch * 64;

      // ---- S = Q @ K^T ----
      floatx4 sf[2][4];
#pragma unroll
      for (int t = 0; t < 4; ++t) {
        const int row8 = (t * 16 + lq) * 8;
        short8 kb0 = *(const short8*)&ksh[buf][(row8 + (quad ^ sw)) * 8];
        short8 kb1 = *(const short8*)&ksh[buf][(row8 + ((quad + 4) ^ sw)) * 8];
#pragma unroll
        for (int rt = 0; rt < 2; ++rt) {
          floatx4 z = (floatx4){0.f, 0.f, 0.f, 0.f};
          z = __builtin_amdgcn_mfma_f32_16x16x32_bf16(qa[rt][0], kb0, z, 0, 0, 0);
          z = __builtin_amdgcn_mfma_f32_16x16x32_bf16(qa[rt][1], kb1, z, 0, 0, 0);
          sf[rt][t] = z;
        }
      }

      // ---- fixed-offset softmax + causal mask ----
#pragma unroll
      for (int rt = 0; rt < 2; ++rt)
#pragma unroll
        for (int t = 0; t < 4; ++t)
#pragma unroll
          for (int r = 0; r < 4; ++r) {
            float p = __expf(sf[rt][t][r] - 4.0f);
            if (s0 + t * 16 + lq > q0 + wave * 32 + rt * 16 + quad * 4 + r)
              p = 0.f;
            lrow[rt][r] += p;
            ps[wave][(rt * 16 + quad * 4 + r) * 72 + t * 16 + lq] = f2bf(p);
          }

      // ---- O += P @ V (P via per-wave LDS round-trip) ----
      short8 pa[2][2];
#pragma unroll
      for (int rt = 0; rt < 2; ++rt) {
        pa[rt][0] = *(const short8*)&ps[wave][(rt * 16 + lq) * 72 + quad * 8];
        pa[rt][1] =
            *(const short8*)&ps[wave][(rt * 16 + lq) * 72 + 32 + quad * 8];
      }
#pragma unroll
      for (int t = 0; t < 4; ++t) {
        const int row8 = (t * 16 + lq) * 8;
        short8 vb0 = *(const short8*)&vsh[buf][(row8 + (quad ^ sw)) * 8];
        short8 vb1 = *(const short8*)&vsh[buf][(row8 + ((quad + 4) ^ sw)) * 8];
#pragma unroll
        for (int rt = 0; rt < 2; ++rt) {
          o[rt][t] = __builtin_amdgcn_mfma_f32_16x16x32_bf16(pa[rt][0], vb0,
                                                             o[rt][t], 0, 0, 0);
          o[rt][t] = __builtin_amdgcn_mfma_f32_16x16x32_bf16(pa[rt][1], vb1,
                                                             o[rt][t], 0, 0, 0);
        }
      }

      if (!have_next) break;
      STAGE_WRITE(buf ^ 1)
      __syncthreads();
      buf ^= 1;
      ch += KS;
    }
  }

#pragma unroll
  for (int rt = 0; rt < 2; ++rt)
#pragma unroll
    for (int r = 0; r < 4; ++r) {
#pragma unroll
      for (int off = 1; off < 16; off <<= 1)
        lrow[rt][r] += __shfl_xor(lrow[rt][r], off);
    }

  const size_t prow = (size_t)((b << kslog) + s) * T_ + q0 + wave * 32;
#pragma unroll
  for (int rt = 0; rt < 2; ++rt) {
#pragma unroll
    for (int t = 0; t < 4; ++t)
#pragma unroll
      for (int r = 0; r < 4; ++r)
        Opart[(prow + rt * 16 + quad * 4 + r) * H_ + t * 16 + lq] =
            o[rt][t][r];
    if (lq == 0) {
#pragma unroll
      for (int r = 0; r < 4; ++r)
        lpart[prow + rt * 16 + quad * 4 + r] = lrow[rt][r];
    }
  }
}

// ---------------------------------------------------------------------------
// Combine: out[b][t][h] = Sum_s Opart / Sum_s lpart. grid 1024 x 256.
// ---------------------------------------------------------------------------
__global__ __launch_bounds__(256) void combine_kernel(
    const float* __restrict__ Opart, const float* __restrict__ lpart,
    float* __restrict__ out, int KS, int kslog) {
  int gid = blockIdx.x * 256 + threadIdx.x;  // 262144 float4 groups
  int b = gid >> 16;
  int rem = gid & 65535;
  int t = rem >> 4;
  int hs = (rem & 15) * 4;
  float sx = 0.f, sy = 0.f, sz = 0.f, sw = 0.f, ls = 0.f;
  for (int s = 0; s < KS; ++s) {
    size_t row = (size_t)((b << kslog) + s) * T_ + t;
    float4 v = *(const float4*)(Opart + row * H_ + hs);
    sx += v.x; sy += v.y; sz += v.z; sw += v.w;
    ls += lpart[row];
  }
  float inv = 1.f / ls;
  float4 o = make_float4(sx * inv, sy * inv, sz * inv, sw * inv);
  *(float4*)(out + ((size_t)b * T_ + t) * H_ + hs) = o;
}

extern "C" void kernel_launch(void* const* d_in, const int* in_sizes, int n_in,
                              void* d_out, int out_size, void* d_ws, size_t ws_size,
                              hipStream_t stream) {
  const float* x = (const float*)d_in[0];
  const float* Wq = (const float*)d_in[1];
  const float* Wk = (const float*)d_in[2];
  const float* Wv = (const float*)d_in[3];
  u16* Qb = (u16*)d_ws;                    // [16384][64] bf16, pre-scaled 1/8
  u16* Kb = Qb + (size_t)NROW * H_;        // [16384][64] bf16
  u16* Vt = Kb + (size_t)NROW * H_;        // [4][64][4096] bf16 (transposed)
  u16* Wb = Vt + (size_t)NROW * H_;        // [192][1024] bf16
  const size_t base = (size_t)3 * NROW * H_ * 2 + 192 * 1024 * 2;  // 6.68 MB

  // split factor: largest of {8,4,2,1} whose partials fit in ws
  int KS = 8;
  while (KS > 1 &&
         base + (size_t)KS * ((size_t)B_ * T_ * H_ * 4 + (size_t)B_ * T_ * 4) >
             ws_size)
    KS >>= 1;
  int kslog = (KS == 8) ? 3 : (KS == 4) ? 2 : (KS == 2) ? 1 : 0;

  float* Opart = (float*)((char*)d_ws + base);          // [B*KS][T][64] fp32
  float* lpart = Opart + (size_t)KS * B_ * T_ * H_;     // [B*KS][T] fp32
  float* out = (float*)d_out;

  cast_w_kernel<<<dim3(192), 256, 0, stream>>>(Wq, Wk, Wv, Wb);
  proj7_kernel<<<dim3(1024), 64, 0, stream>>>(x, Wb, Qb, Kb, Vt);
  attn_kernel<<<dim3(32, B_ * KS), 256, 0, stream>>>(Qb, Kb, Vt, Opart, lpart,
                                                     KS, kslog);
  combine_kernel<<<dim3(1024), 256, 0, stream>>>(Opart, lpart, out, KS, kslog);
}

// Round 9
// 154.972 us; speedup vs baseline: 1.2554x; 1.2065x over previous
//
#include <hip/hip_runtime.h>
#include <math.h>

#define B_ 4
#define T_ 4096
#define C_ 1024
#define H_ 64
#define NROW (B_ * T_)  // 16384

typedef unsigned short u16;
typedef __attribute__((ext_vector_type(8))) short short8;
typedef __attribute__((ext_vector_type(4))) float floatx4;
typedef __attribute__((ext_vector_type(8))) unsigned short ushortx8;
typedef __attribute__((ext_vector_type(4))) unsigned short ushortx4;

__device__ __forceinline__ u16 f2bf(float f) {  // RNE
  unsigned int u = __builtin_bit_cast(unsigned int, f);
  unsigned int r = (u + 0x7FFFu + ((u >> 16) & 1u)) >> 16;
  return (u16)r;
}

// ---------------------------------------------------------------------------
// Cast Wq|Wk|Wv fp32 -> Wb bf16 [192][1024]. grid 192 x 256.
// ---------------------------------------------------------------------------
__global__ __launch_bounds__(256) void cast_w_kernel(
    const float* __restrict__ Wq, const float* __restrict__ Wk,
    const float* __restrict__ Wv, u16* __restrict__ Wb) {
  int i = blockIdx.x * 256 + threadIdx.x;  // float4 index, 49152 total
  const float* src = (i < 16384) ? Wq : ((i < 32768) ? Wk : Wv);
  int j = i & 16383;
  float4 v = ((const float4*)src)[j];
  ushortx4 o = {f2bf(v.x), f2bf(v.y), f2bf(v.z), f2bf(v.w)};
  *(ushortx4*)(Wb + (size_t)i * 4) = o;
}

// ---------------------------------------------------------------------------
// QKV projection v9. Block = 256 thr (4 waves) = 64 rows x 192 cols, K=1024.
// grid 256 (1 block/CU; LDS 128 KB).
//  - x row-tile staged ONCE into XOR-swizzled LDS (bf16): 16B chunk (r,c) at
//    slot r*128 + (c ^ (r&7)). Swizzle kills the 16-way same-column ds_read
//    conflict of a 2048B-stride layout; staging writes stay conflict-free.
//  - Each wave owns only 3 column-tiles (48 cols): W read/wave = 96 KB, so
//    block W traffic = 384 KB and chip total = 96 MB L2 (R8's proj7 pulled
//    384 KB PER WAVE = 384 MB L2 with a depth-2 ring -> 60 us, MfmaUtil 3.5%).
//  - W B-frags: use-then-fill depth-4 register ring (12 int4), preloaded
//    BEFORE x staging so in-order vmcnt retires them under the x stream.
//  - k-loop has NO barriers: A from LDS (lgkm), W from L2 (vmem ring).
//  - Epilogue = R7 projcomb's verified store block, sm aliased over xs.
// ---------------------------------------------------------------------------
__global__ __launch_bounds__(256) void proj9_kernel(
    const float* __restrict__ x, const u16* __restrict__ Wb,
    u16* __restrict__ Qb, u16* __restrict__ Kb, u16* __restrict__ Vt) {
  const int m0 = (int)blockIdx.x * 64;
  const int tid = threadIdx.x;
  const int wave = tid >> 6, lane = tid & 63;
  const int lq = lane & 15, quad = lane >> 4;

  __shared__ __align__(16) u16 xs[64 * 1024];  // 128 KB

  // ---- W ring preload (issued first; completes under x staging) ----
  const u16* wp0 = Wb + (size_t)((wave * 3 + 0) * 16 + lq) * C_ + quad * 8;
  const u16* wp1 = Wb + (size_t)((wave * 3 + 1) * 16 + lq) * C_ + quad * 8;
  const u16* wp2 = Wb + (size_t)((wave * 3 + 2) * 16 + lq) * C_ + quad * 8;
  short8 wf[4][3];
#pragma unroll
  for (int d = 0; d < 4; ++d) {
    wf[d][0] = *(const short8*)(wp0 + d * 32);
    wf[d][1] = *(const short8*)(wp1 + d * 32);
    wf[d][2] = *(const short8*)(wp2 + d * 32);
  }

  // ---- stage x fp32->bf16 into swizzled LDS (coalesced, deep pipeline) ----
#pragma unroll 4
  for (int i = 0; i < 32; ++i) {
    int g = i * 256 + tid;      // 16B-bf16 chunk id
    int row = g >> 7, c = g & 127;
    const float* src = x + (size_t)(m0 + row) * C_ + c * 8;
    float4 a = *(const float4*)(src);
    float4 b = *(const float4*)(src + 4);
    ushortx8 v = {f2bf(a.x), f2bf(a.y), f2bf(a.z), f2bf(a.w),
                  f2bf(b.x), f2bf(b.y), f2bf(b.z), f2bf(b.w)};
    *(ushortx8*)&xs[(row * 128 + (c ^ (row & 7))) * 8] = v;
  }
  __syncthreads();

  floatx4 acc[4][3];
#pragma unroll
  for (int rt = 0; rt < 4; ++rt)
#pragma unroll
    for (int j = 0; j < 3; ++j) acc[rt][j] = (floatx4){0.f, 0.f, 0.f, 0.f};

  // ---- k-loop: 32 steps of k=32; use slot s&3, then refill for s+4 ----
#pragma unroll
  for (int s = 0; s < 32; ++s) {
    short8 af[4];
#pragma unroll
    for (int rt = 0; rt < 4; ++rt) {
      int row = rt * 16 + lq;
      int c = (s * 4 + quad) ^ (lq & 7);
      af[rt] = *(const short8*)&xs[(row * 128 + c) * 8];
    }
    const int sl = s & 3;
#pragma unroll
    for (int j = 0; j < 3; ++j) {
      short8 bf = wf[sl][j];
#pragma unroll
      for (int rt = 0; rt < 4; ++rt)
        acc[rt][j] =
            __builtin_amdgcn_mfma_f32_16x16x32_bf16(af[rt], bf, acc[rt][j], 0, 0, 0);
    }
    if (s + 4 < 32) {  // refill the slot just consumed
      wf[sl][0] = *(const short8*)(wp0 + (s + 4) * 32);
      wf[sl][1] = *(const short8*)(wp1 + (s + 4) * 32);
      wf[sl][2] = *(const short8*)(wp2 + (s + 4) * 32);
    }
  }

  // ---- epilogue: acc -> sm (aliased over xs) -> coalesced stores ----
  __syncthreads();  // all waves done reading xs
  u16(*sm)[208] = (u16(*)[208])xs;
#pragma unroll
  for (int j = 0; j < 3; ++j) {
    const int gc = (wave * 3 + j) * 16;          // 16-col tile, never straddles
    const float sc = (gc < 64) ? 0.125f : 1.0f;  // fold 64^-0.5 into Q
#pragma unroll
    for (int rt = 0; rt < 4; ++rt)
#pragma unroll
      for (int r = 0; r < 4; ++r)
        sm[rt * 16 + quad * 4 + r][gc + lq] = f2bf(acc[rt][j][r] * sc);
  }
  __syncthreads();

  // R7 projcomb's verified store block
  const int row = tid >> 2, hseg = (tid & 3) * 16;
  {
    ushortx8 w0 = *(const ushortx8*)&sm[row][hseg];
    ushortx8 w1 = *(const ushortx8*)&sm[row][hseg + 8];
    u16* dq = Qb + (size_t)(m0 + row) * H_ + hseg;
    *(ushortx8*)dq = w0;
    *(ushortx8*)(dq + 8) = w1;
  }
  {
    ushortx8 w0 = *(const ushortx8*)&sm[row][64 + hseg];
    ushortx8 w1 = *(const ushortx8*)&sm[row][64 + hseg + 8];
    u16* dk = Kb + (size_t)(m0 + row) * H_ + hseg;
    *(ushortx8*)dk = w0;
    *(ushortx8*)(dk + 8) = w1;
  }
  {
    const int h = tid >> 2, tseg = (tid & 3) * 16;
    u16 tmp[16];
#pragma unroll
    for (int tt = 0; tt < 16; ++tt) tmp[tt] = sm[tseg + tt][128 + h];
    ushortx8 w0, w1;
#pragma unroll
    for (int tt = 0; tt < 8; ++tt) { w0[tt] = tmp[tt]; w1[tt] = tmp[8 + tt]; }
    const int bb = m0 >> 12, t0 = m0 & 4095;
    u16* dv = Vt + ((size_t)bb * H_ + h) * T_ + t0 + tseg;
    *(ushortx8*)dv = w0;
    *(ushortx8*)(dv + 8) = w1;
  }
}

// ---------------------------------------------------------------------------
// Flash attention v3 (unchanged, R7-verified). Block = 256 thr (4 waves),
// Q-tile 128. K/V chunks staged into XOR-swizzled LDS, double-buffered, one
// barrier/chunk. Split-K (fixed-offset softmax p=exp(s-4): partials add).
// grid (32, B*KS).
// ---------------------------------------------------------------------------
__global__ __launch_bounds__(256) void attn_kernel(
    const u16* __restrict__ Qb, const u16* __restrict__ Kb,
    const u16* __restrict__ Vt, float* __restrict__ Opart,
    float* __restrict__ lpart, int KS, int kslog) {
  const int tau = (int)gridDim.x - 1 - (int)blockIdx.x;  // LPT: heavy first
  const int q0 = tau * 128;
  const int b = (int)blockIdx.y >> kslog;
  const int s = (int)blockIdx.y & (KS - 1);
  const int tid = threadIdx.x;
  const int wave = tid >> 6, lane = tid & 63;
  const int lq = lane & 15, quad = lane >> 4;
  const int sw = lq & 7;

  __shared__ __align__(16) u16 ksh[2][64 * 64];
  __shared__ __align__(16) u16 vsh[2][64 * 64];
  __shared__ __align__(16) u16 ps[4][32 * 72];

  const int nch = 2 * tau + 2;  // 64-key chunks incl. diagonal
  const u16* Kb_b = Kb + (size_t)b * T_ * H_;
  const u16* Vt_b = Vt + (size_t)b * H_ * T_;

  short8 qa[2][2];
#pragma unroll
  for (int rt = 0; rt < 2; ++rt) {
    const u16* qrow =
        Qb + ((size_t)b * T_ + q0 + wave * 32 + rt * 16 + lq) * H_;
    qa[rt][0] = *(const short8*)(qrow + quad * 8);
    qa[rt][1] = *(const short8*)(qrow + 32 + quad * 8);
  }

  floatx4 o[2][4];
  float lrow[2][4];
#pragma unroll
  for (int rt = 0; rt < 2; ++rt)
#pragma unroll
    for (int t = 0; t < 4; ++t) {
      o[rt][t] = (floatx4){0.f, 0.f, 0.f, 0.f};
      lrow[rt][t] = 0.f;
    }

  const int srow = tid >> 3;  // 0..31
  const int sseg = tid & 7;
  const int spos0 = (srow * 8 + (sseg ^ (srow & 7))) * 8;  // u16 index
  const int spos1 = spos0 + 2048;                          // row+32, same xor

  int4 kst0, kst1, vst0, vst1;
#define STAGE_LOAD(S0)                                                        \
  {                                                                           \
    kst0 = *(const int4*)(Kb_b + (size_t)((S0) + srow) * H_ + sseg * 8);      \
    kst1 = *(const int4*)(Kb_b + (size_t)((S0) + srow + 32) * H_ + sseg * 8); \
    vst0 = *(const int4*)(Vt_b + (size_t)srow * T_ + (S0) + sseg * 8);        \
    vst1 = *(const int4*)(Vt_b + (size_t)(srow + 32) * T_ + (S0) + sseg * 8); \
  }
#define STAGE_WRITE(BUF)                                                      \
  {                                                                           \
    *(int4*)&ksh[BUF][spos0] = kst0;                                          \
    *(int4*)&ksh[BUF][spos1] = kst1;                                          \
    *(int4*)&vsh[BUF][spos0] = vst0;                                          \
    *(int4*)&vsh[BUF][spos1] = vst1;                                          \
  }

  int ch = s, buf = 0;
  if (ch < nch) {
    STAGE_LOAD(ch * 64)
    STAGE_WRITE(0)
  }
  __syncthreads();

  if (ch < nch) {
    for (;;) {
      const bool have_next = (ch + KS < nch);
      if (have_next) { STAGE_LOAD((ch + KS) * 64) }
      const int s0 = ch * 64;

      floatx4 sf[2][4];
#pragma unroll
      for (int t = 0; t < 4; ++t) {
        const int row8 = (t * 16 + lq) * 8;
        short8 kb0 = *(const short8*)&ksh[buf][(row8 + (quad ^ sw)) * 8];
        short8 kb1 = *(const short8*)&ksh[buf][(row8 + ((quad + 4) ^ sw)) * 8];
#pragma unroll
        for (int rt = 0; rt < 2; ++rt) {
          floatx4 z = (floatx4){0.f, 0.f, 0.f, 0.f};
          z = __builtin_amdgcn_mfma_f32_16x16x32_bf16(qa[rt][0], kb0, z, 0, 0, 0);
          z = __builtin_amdgcn_mfma_f32_16x16x32_bf16(qa[rt][1], kb1, z, 0, 0, 0);
          sf[rt][t] = z;
        }
      }

#pragma unroll
      for (int rt = 0; rt < 2; ++rt)
#pragma unroll
        for (int t = 0; t < 4; ++t)
#pragma unroll
          for (int r = 0; r < 4; ++r) {
            float p = __expf(sf[rt][t][r] - 4.0f);
            if (s0 + t * 16 + lq > q0 + wave * 32 + rt * 16 + quad * 4 + r)
              p = 0.f;
            lrow[rt][r] += p;
            ps[wave][(rt * 16 + quad * 4 + r) * 72 + t * 16 + lq] = f2bf(p);
          }

      short8 pa[2][2];
#pragma unroll
      for (int rt = 0; rt < 2; ++rt) {
        pa[rt][0] = *(const short8*)&ps[wave][(rt * 16 + lq) * 72 + quad * 8];
        pa[rt][1] =
            *(const short8*)&ps[wave][(rt * 16 + lq) * 72 + 32 + quad * 8];
      }
#pragma unroll
      for (int t = 0; t < 4; ++t) {
        const int row8 = (t * 16 + lq) * 8;
        short8 vb0 = *(const short8*)&vsh[buf][(row8 + (quad ^ sw)) * 8];
        short8 vb1 = *(const short8*)&vsh[buf][(row8 + ((quad + 4) ^ sw)) * 8];
#pragma unroll
        for (int rt = 0; rt < 2; ++rt) {
          o[rt][t] = __builtin_amdgcn_mfma_f32_16x16x32_bf16(pa[rt][0], vb0,
                                                             o[rt][t], 0, 0, 0);
          o[rt][t] = __builtin_amdgcn_mfma_f32_16x16x32_bf16(pa[rt][1], vb1,
                                                             o[rt][t], 0, 0, 0);
        }
      }

      if (!have_next) break;
      STAGE_WRITE(buf ^ 1)
      __syncthreads();
      buf ^= 1;
      ch += KS;
    }
  }

#pragma unroll
  for (int rt = 0; rt < 2; ++rt)
#pragma unroll
    for (int r = 0; r < 4; ++r) {
#pragma unroll
      for (int off = 1; off < 16; off <<= 1)
        lrow[rt][r] += __shfl_xor(lrow[rt][r], off);
    }

  const size_t prow = (size_t)((b << kslog) + s) * T_ + q0 + wave * 32;
#pragma unroll
  for (int rt = 0; rt < 2; ++rt) {
#pragma unroll
    for (int t = 0; t < 4; ++t)
#pragma unroll
      for (int r = 0; r < 4; ++r)
        Opart[(prow + rt * 16 + quad * 4 + r) * H_ + t * 16 + lq] =
            o[rt][t][r];
    if (lq == 0) {
#pragma unroll
      for (int r = 0; r < 4; ++r)
        lpart[prow + rt * 16 + quad * 4 + r] = lrow[rt][r];
    }
  }
}

// ---------------------------------------------------------------------------
// Combine: out[b][t][h] = Sum_s Opart / Sum_s lpart. grid 1024 x 256.
// ---------------------------------------------------------------------------
__global__ __launch_bounds__(256) void combine_kernel(
    const float* __restrict__ Opart, const float* __restrict__ lpart,
    float* __restrict__ out, int KS, int kslog) {
  int gid = blockIdx.x * 256 + threadIdx.x;  // 262144 float4 groups
  int b = gid >> 16;
  int rem = gid & 65535;
  int t = rem >> 4;
  int hs = (rem & 15) * 4;
  float sx = 0.f, sy = 0.f, sz = 0.f, sw = 0.f, ls = 0.f;
  for (int s = 0; s < KS; ++s) {
    size_t row = (size_t)((b << kslog) + s) * T_ + t;
    float4 v = *(const float4*)(Opart + row * H_ + hs);
    sx += v.x; sy += v.y; sz += v.z; sw += v.w;
    ls += lpart[row];
  }
  float inv = 1.f / ls;
  float4 o = make_float4(sx * inv, sy * inv, sz * inv, sw * inv);
  *(float4*)(out + ((size_t)b * T_ + t) * H_ + hs) = o;
}

extern "C" void kernel_launch(void* const* d_in, const int* in_sizes, int n_in,
                              void* d_out, int out_size, void* d_ws, size_t ws_size,
                              hipStream_t stream) {
  const float* x = (const float*)d_in[0];
  const float* Wq = (const float*)d_in[1];
  const float* Wk = (const float*)d_in[2];
  const float* Wv = (const float*)d_in[3];
  u16* Qb = (u16*)d_ws;                    // [16384][64] bf16, pre-scaled 1/8
  u16* Kb = Qb + (size_t)NROW * H_;        // [16384][64] bf16
  u16* Vt = Kb + (size_t)NROW * H_;        // [4][64][4096] bf16 (transposed)
  u16* Wb = Vt + (size_t)NROW * H_;        // [192][1024] bf16
  const size_t base = (size_t)3 * NROW * H_ * 2 + 192 * 1024 * 2;  // 6.68 MB

  // split factor: largest of {8,4,2,1} whose partials fit in ws
  int KS = 8;
  while (KS > 1 &&
         base + (size_t)KS * ((size_t)B_ * T_ * H_ * 4 + (size_t)B_ * T_ * 4) >
             ws_size)
    KS >>= 1;
  int kslog = (KS == 8) ? 3 : (KS == 4) ? 2 : (KS == 2) ? 1 : 0;

  float* Opart = (float*)((char*)d_ws + base);          // [B*KS][T][64] fp32
  float* lpart = Opart + (size_t)KS * B_ * T_ * H_;     // [B*KS][T] fp32
  float* out = (float*)d_out;

  cast_w_kernel<<<dim3(192), 256, 0, stream>>>(Wq, Wk, Wv, Wb);
  proj9_kernel<<<dim3(256), 256, 0, stream>>>(x, Wb, Qb, Kb, Vt);
  attn_kernel<<<dim3(32, B_ * KS), 256, 0, stream>>>(Qb, Kb, Vt, Opart, lpart,
                                                     KS, kslog);
  combine_kernel<<<dim3(1024), 256, 0, stream>>>(Opart, lpart, out, KS, kslog);
}